// Round 10
// baseline (160.543 us; speedup 1.0000x reference)
//
#include <hip/hip_runtime.h>
#include <hip/hip_fp16.h>

typedef __attribute__((ext_vector_type(8))) _Float16 half8; // 8 x f16 (4 VGPRs, MFMA A/B)
typedef __attribute__((ext_vector_type(2))) _Float16 h2v;   // packed f16 pair (1 VGPR)
typedef __attribute__((ext_vector_type(4))) float floatx4;  // MFMA acc

#define PXN 204         // logical pixels: 6 rows x 34 (h=4 tile + halo)
#define QBASE 26128     // Q region at 26112+16: +16 staggers Q bank quads by 1 vs P
// LDS map (52,240 B total):
//   P region [204][128B] at 0      : chunk g = channels g*16..+7 (f16)
//   Q region [204][128B] at 26128  : chunk g = channels g*16+8..+15
//   chunk swizzle: physical 16B-chunk = logical ^ (px & 7)
// ROUND-10 STRUCTURE: 512-thread blocks, SAME 52KB tile. Phase B splits 16 ways
// by channel (thread owns ONE uint4/pixel; 16-lane score butterfly). Halves the
// per-thread window state (36 VGPR) and critical path; at VGPR<=85 the CU fits
// 3 blocks x 8 waves = 24 waves/CU = 6 waves/SIMD (2x round 9's latency hiding).
// Direct A-gather from global (no x LDS staging); ONE barrier per block.
// Phase B BARRIER-FREE; direct per-channel stores merge to full lines in L2
// (verified r5: WRITE_SIZE == output exactly).
// LAUNCH BOUNDS (measured r3-r6): 2nd arg 2 -> VGPR cap 128, no spill;
// 3 -> cap 84; 4 -> cap 64 = total spill. Keep (512,2).

__device__ __forceinline__ ushort f2h(float f) {
    union { _Float16 h; ushort u; } cv;
    cv.h = (_Float16)f;
    return cv.u;
}
__device__ __forceinline__ h2v as_h2(unsigned int u) {
    union { unsigned int u; h2v h; } cv;
    cv.u = u;
    return cv.h;
}

// 16-lane (same-pixel, all channel chunks) reduce: xor1/xor2 on VALU via DPP
// quad_perm; xor4/xor8 via shfl (LDS pipe).
__device__ __forceinline__ float gsum16(float v) {
    v += __int_as_float(__builtin_amdgcn_update_dpp(0, __float_as_int(v), 0xB1, 0xF, 0xF, false)); // xor1
    v += __int_as_float(__builtin_amdgcn_update_dpp(0, __float_as_int(v), 0x4E, 0xF, 0xF, false)); // xor2
    v += __shfl_xor(v, 4);
    v += __shfl_xor(v, 8);
    return v;
}

// ---- phase-B building blocks (macros: compile-time slot indices -> registers) ----
// thread (g 0..15, ox 0..31): gp = g&7 chunk, hi = g>>3 region; 8 channels
// c = gp*16 + hi*8 + j. One uint4 per pixel.
#define LOADROW(S, PROW)                                                            \
    {                                                                               \
        _Pragma("unroll")                                                           \
        for (int dx = 0; dx < 3; ++dx) {                                            \
            int pi = (PROW) * 34 + ox + dx;                                         \
            w[S][dx] = *(const uint4*)(rbase + pi * 128 + ((gp * 16) ^ ((pi & 7) << 4))); \
        }                                                                           \
    }

// score partial over this thread's 8 channels: 4 x v_dot2_f32_f16, split accums
#define SCORE1(S, DX) ({                                                            \
        uint4 _u = w[S][DX];                                                        \
        float _s0 = 0.f, _s1 = 0.f;                                                 \
        _s0 = __builtin_amdgcn_fdot2(as_h2(_u.x), cf[0], _s0, false);               \
        _s1 = __builtin_amdgcn_fdot2(as_h2(_u.y), cf[1], _s1, false);               \
        _s0 = __builtin_amdgcn_fdot2(as_h2(_u.z), cf[2], _s0, false);               \
        _s1 = __builtin_amdgcn_fdot2(as_h2(_u.w), cf[3], _s1, false);               \
        _s0 + _s1; })

// PV: fmaf(half2float(x), a, o) pattern-fuses to v_fma_mix_f32 (no separate cvt)
#define PVU(U, A, O0, O1)                                                           \
    { h2v _v = as_h2(U);                                                            \
      O0 = fmaf((float)_v.x, (A), O0); O1 = fmaf((float)_v.y, (A), O1); }
#define PV(S, DX, A)                                                                \
    {                                                                               \
        uint4 _p = w[S][DX];                                                        \
        PVU(_p.x, A, o[0], o[1])  PVU(_p.y, A, o[2], o[3])                          \
        PVU(_p.z, A, o[4], o[5])  PVU(_p.w, A, o[6], o[7])                          \
    }

#define ATTN_OY(OY, ST, SM, SB)                                                     \
    {                                                                               \
        h2v cf[4];                                                                  \
        {                                                                           \
            uint4 c0 = w[SM][1];                                                    \
            cf[0] = as_h2(c0.x); cf[1] = as_h2(c0.y);                               \
            cf[2] = as_h2(c0.z); cf[3] = as_h2(c0.w);                               \
        }                                                                           \
        float s[9];                                                                 \
        s[0] = SCORE1(ST, 0); s[1] = SCORE1(ST, 1); s[2] = SCORE1(ST, 2);           \
        s[3] = SCORE1(SM, 0); s[4] = SCORE1(SM, 1); s[5] = SCORE1(SM, 2);           \
        s[6] = SCORE1(SB, 0); s[7] = SCORE1(SB, 1); s[8] = SCORE1(SB, 2);           \
        _Pragma("unroll")                                                           \
        for (int n = 0; n < 9; ++n)                                                 \
            s[n] = gsum16(s[n]) * 0.08838834764831845f;  /* 1/sqrt(128) */          \
        float m = fmaxf(fmaxf(fmaxf(fmaxf(s[0], s[1]), s[2]),       /* v_max3 */    \
                              fmaxf(fmaxf(s[3], s[4]), s[5])),                      \
                        fmaxf(fmaxf(s[6], s[7]), s[8]));                            \
        float e[9], sum = 0.f;                                                      \
        _Pragma("unroll")                                                           \
        for (int n = 0; n < 9; ++n) { e[n] = __expf(s[n] - m); sum += e[n]; }       \
        float o[8];                                                                 \
        _Pragma("unroll")                                                           \
        for (int j = 0; j < 8; ++j) o[j] = 0.f;                                     \
        PV(ST, 0, e[0]) PV(ST, 1, e[1]) PV(ST, 2, e[2])                             \
        PV(SM, 0, e[3]) PV(SM, 1, e[4]) PV(SM, 2, e[5])                             \
        PV(SB, 0, e[6]) PV(SB, 1, e[7]) PV(SB, 2, e[8])                             \
        float inv = 1.f / sum;                                                      \
        float* og = out + ((size_t)((b * 128 + gp * 16 + hi * 8) * 128              \
                    + (h0 + (OY)))) * 128 + w0 + ox;                                \
        _Pragma("unroll")                                                           \
        for (int j = 0; j < 8; ++j)                                                 \
            og[j * 16384] = o[j] * inv;                                             \
    }

__global__ __launch_bounds__(512, 2)
void attn_conv_fused(const float* __restrict__ x, const float* __restrict__ Wc,
                     const float* __restrict__ bc, float* __restrict__ out) {
    __shared__ __align__(16) unsigned char smem[52240];
    char* smc = (char*)smem;

    const int tid = threadIdx.x;
    // XCD-chunked swizzle (bijective, 1024 = 8*128): XCD k owns batch k entirely;
    // within an XCD, w-tiles fastest then h-bands -> halo rows stay L2-resident.
    const int rid = ((blockIdx.x & 7) << 7) | (blockIdx.x >> 3);
    const int b   = rid >> 7;
    const int h0  = ((rid >> 2) & 31) * 4;
    const int w0  = (rid & 3) * 32;
    const int lane = tid & 63;
    const int wv   = tid >> 6;                // 0..7
    const int col = lane & 15;
    const int kq  = lane >> 4;

    // ---------------- Phase A-direct: gather A-fragments from global ---------
    // 13 m-tiles over 8 waves: wave wv handles mt = wv and (wv<5) wv+8.
    // Clamped addrs; OOB pixel rows masked to 0 at the y-write.
    half8 af0[2], af1[2];
    #pragma unroll
    for (int i = 0; i < 2; ++i) {
        int mt = wv + i * 8;
        if (mt < 13) {
            int px  = mt * 16 + col;
            int py  = (px * 965) >> 15;           // px / 34 (exact for px<208)
            int pxx = px - py * 34;
            int gh = min(max(h0 + py - 1, 0), 127);
            int gw = min(max(w0 + pxx - 1, 0), 127);
            const float* xp = x + (size_t)(b * 64) * 16384 + gh * 128 + gw;
            #pragma unroll
            for (int j = 0; j < 8; ++j) {
                af0[i][j] = (_Float16)xp[(kq * 8 + j) << 14];
                af1[i][j] = (_Float16)xp[(32 + kq * 8 + j) << 14];
            }
        }
    }

    // ---------------- Phase A1: W fragments (B-operand) from global ----------
    half8 bw[8][2];
    float bias[8];
    #pragma unroll
    for (int t = 0; t < 8; ++t) {
        int c = t * 16 + col;
        bias[t] = bc[c];
        #pragma unroll
        for (int half = 0; half < 2; ++half) {
            const float* wp = Wc + c * 64 + half * 32 + kq * 8;
            float4 wa = *(const float4*)wp;
            float4 wb = *(const float4*)(wp + 4);
            half8 f;
            f[0] = (_Float16)wa.x; f[1] = (_Float16)wa.y;
            f[2] = (_Float16)wa.z; f[3] = (_Float16)wa.w;
            f[4] = (_Float16)wb.x; f[5] = (_Float16)wb.y;
            f[6] = (_Float16)wb.z; f[7] = (_Float16)wb.w;
            bw[t][half] = f;
        }
    }

    // ---------------- Phase A2: MFMA conv -> P/Q f16 (swizzled) --------------
    // channel c = t*16+col -> region (col<8 ? P : Q), chunk t ^ (pxr&7), slot col&7
    char* wbase = smc + (col < 8 ? 0 : QBASE);
    const int cb2 = (col & 7) * 2;
    #pragma unroll
    for (int i = 0; i < 2; ++i) {
        int mt = wv + i * 8;
        if (mt < 13) {
            floatx4 acc[8];
            #pragma unroll
            for (int t = 0; t < 8; ++t) acc[t] = (floatx4){0.f, 0.f, 0.f, 0.f};
            #pragma unroll
            for (int t = 0; t < 8; ++t) {
                acc[t] = __builtin_amdgcn_mfma_f32_16x16x32_f16(af0[i], bw[t][0], acc[t], 0, 0, 0);
                acc[t] = __builtin_amdgcn_mfma_f32_16x16x32_f16(af1[i], bw[t][1], acc[t], 0, 0, 0);
            }
            #pragma unroll
            for (int r = 0; r < 4; ++r) {
                int pxr = mt * 16 + kq * 4 + r;   // D row = (lane>>4)*4 + r
                if (pxr < PXN) {
                    int py  = (pxr * 965) >> 15;
                    int pxx = pxr - py * 34;
                    int gh = h0 + py - 1, gw = w0 + pxx - 1;
                    bool inb = (gh >= 0 && gh < 128 && gw >= 0 && gw < 128);
                    char* prow = wbase + pxr * 128;
                    int swz = (pxr & 7) << 4;
                    #pragma unroll
                    for (int t = 0; t < 8; ++t)
                        *(ushort*)(prow + (((t * 16) ^ swz) + cb2)) =
                            f2h(inb ? (acc[t][r] + bias[t]) : 0.f);
                }
            }
        }
    }
    __syncthreads();   // THE ONLY BARRIER: y complete -> phase B reads

    // ---------------- Phase B: 3x3 local attention, barrier-free -------------
    // thread (g 0..15, ox 0..31): 8 channels (chunk gp of region hi), pixel
    // column ox; patch window (ONE uint4/pixel) carried in registers across oy.
    const int g  = tid & 15;
    const int ox = tid >> 4;                  // 0..31
    const int gp = g & 7;
    const int hi = g >> 3;
    const char* rbase = smc + (hi ? QBASE : 0);
    uint4 w[3][3];                            // [row slot][dx]

    LOADROW(0, 0) LOADROW(1, 1) LOADROW(2, 2)
    ATTN_OY(0, 0, 1, 2)
    LOADROW(0, 3)
    ATTN_OY(1, 1, 2, 0)
    LOADROW(1, 4)
    ATTN_OY(2, 2, 0, 1)
    LOADROW(2, 5)
    ATTN_OY(3, 0, 1, 2)
}

extern "C" void kernel_launch(void* const* d_in, const int* in_sizes, int n_in,
                              void* d_out, int out_size, void* d_ws, size_t ws_size,
                              hipStream_t stream) {
    const float* x  = (const float*)d_in[0];
    const float* Wc = (const float*)d_in[1];
    const float* bc = (const float*)d_in[2];
    float* out = (float*)d_out;

    dim3 grid(1024);         // flat; XCD-chunked decode in-kernel (h=4, w=32 tiles)
    dim3 block(512);
    attn_conv_fused<<<grid, block, 0, stream>>>(x, Wc, bc, out);
}